// Round 17
// baseline (483.143 us; speedup 1.0000x reference)
//
#include <hip/hip_runtime.h>
#include <hip/hip_bf16.h>

#define DI __device__ __forceinline__

typedef unsigned short u16;
typedef __attribute__((ext_vector_type(4))) float f32x4;
typedef __attribute__((ext_vector_type(8))) short short8;
typedef __attribute__((ext_vector_type(4))) short short4v;

constexpr int Bb = 16, Tt = 8192;
constexpr int M_TOT = Bb * Tt; // 131072

static DI u16 f2bf(float f) {
    union { float f; unsigned u; } v; v.f = f;
    unsigned r = v.u + 0x7fffu + ((v.u >> 16) & 1u);
    return (u16)(r >> 16);
}
static DI float bf2f(u16 u) {
    union { unsigned u; float f; } v; v.u = ((unsigned)u) << 16;
    return v.f;
}
static DI float bf2f_s(short s) { return bf2f((u16)s); }

static DI void lds_load16(const void* g, void* l) {
    __builtin_amdgcn_global_load_lds(
        (const __attribute__((address_space(1))) void*)g,
        (__attribute__((address_space(3))) void*)l, 16, 0, 0);
}

// tanh-approx gelu, exp2 with folded constants: |err| <= ~1e-3 abs
static DI float gelu_fast(float x) {
    float x2 = x * x;
    float z2 = x * (2.30220723f + 0.10294515f * x2);  // 2*sqrt(2/pi)*log2e*(1+0.044715x^2)
    float e;
    asm("v_exp_f32 %0, %1" : "=v"(e) : "v"(z2));      // e = 2^z2 = e^{2z}
    float r = __builtin_amdgcn_rcpf(1.f + e);
    return x - x * r;                                  // x*e/(1+e)
}

// ---------------- weight prep: transpose + bf16 + LN-fold + colsum ----------------
__global__ void prep_weights(const float* __restrict__ Wm, const float* __restrict__ Wp,
                             const float* __restrict__ W1, const float* __restrict__ W2,
                             const float* __restrict__ Wc,
                             const float* __restrict__ g1, const float* __restrict__ b1,
                             const float* __restrict__ g2, const float* __restrict__ b2,
                             const float* __restrict__ bm, const float* __restrict__ bf1,
                             u16* __restrict__ WmT, u16* __restrict__ WpT,
                             u16* __restrict__ W1T, u16* __restrict__ W2T,
                             u16* __restrict__ WtC,
                             float* __restrict__ bmF, float* __restrict__ b1F,
                             float* __restrict__ colsum) {
    int i = blockIdx.x * blockDim.x + threadIdx.x;
    int stride = gridDim.x * blockDim.x;
    for (int j = i; j < 512 * 256; j += stride) {       // WmT[n][k] = g1[k]*Wm[k][n]
        int n = j >> 8, k = j & 255;
        WmT[j] = f2bf(Wm[k * 512 + n] * g1[k]);
    }
    for (int j = i; j < 256 * 256; j += stride) {       // WpT
        int n = j >> 8, k = j & 255;
        WpT[j] = f2bf(Wp[k * 256 + n]);
    }
    for (int j = i; j < 1024 * 256; j += stride) {      // W1T[n][k] = g2[k]*W1[k][n]
        int n = j >> 8, k = j & 255;
        W1T[j] = f2bf(W1[k * 1024 + n] * g2[k]);
    }
    for (int j = i; j < 256 * 1024; j += stride) {      // W2T[n][k] = W2[k][n]
        int n = j >> 10, k = j & 1023;
        W2T[j] = f2bf(W2[k * 256 + n]);
    }
    for (int j = i; j < 128 * 128; j += stride) {       // conv weights: [co][k'=tap*16+ci]
        int co = j >> 7, kp = j & 127;
        int tap = kp >> 4, ci = kp & 15;
        float v = (tap < 7) ? Wc[(co * 16 + ci) * 7 + tap] : 0.f;
        WtC[j] = f2bf(v);
    }
    for (int n = i; n < 512; n += stride) {             // bmF = bm + b1 @ Wm ; colsum = g1 @ Wm col
        float s = bm[n], cs = 0.f;
        for (int k = 0; k < 256; ++k) {
            s += b1[k] * Wm[k * 512 + n];
            cs += g1[k] * Wm[k * 512 + n];
        }
        bmF[n] = s;
        colsum[n] = cs;
    }
    for (int n = i; n < 1024; n += stride) {            // b1F = bf1 + b2 @ W1
        float s = bf1[n];
        for (int k = 0; k < 256; ++k) s += b2[k] * W1[k * 1024 + n];
        b1F[n] = s;
    }
}

// ---------------- LN1-lite: transpose (B,C,T)->(B*T,C) bf16 + per-row (mean, rstd) ----
__global__ __launch_bounds__(256) void ln1_kernel(const float* __restrict__ x,
                                                  u16* __restrict__ xt,
                                                  float* __restrict__ mbuf,
                                                  float* __restrict__ rbuf) {
    __shared__ u16 tile[64 * 256];            // [t][c], XOR-swizzled in 16B slots
    __shared__ float ps[64 * 16], pss[64 * 16];
    int bidx = blockIdx.x;
    int b = bidx >> 7;
    int t0 = (bidx & 127) << 6;
    int tid = threadIdx.x, l = tid & 63, w = tid >> 6;
    int lr = l & 15, lg = l >> 4;
    float s[4] = {}, ss[4] = {};
    #pragma unroll 4
    for (int it = 0; it < 16; ++it) {
        int c = it * 16 + w * 4 + lg;
        f32x4 v = *(const f32x4*)&x[((size_t)b * 256 + c) * 8192 + t0 + lr * 4];
        #pragma unroll
        for (int k = 0; k < 4; ++k) {
            s[k] += v[k]; ss[k] += v[k] * v[k];
            int t = lr * 4 + k;
            int c8 = c >> 3;
            int slot = (c8 & 24) | ((c8 ^ t) & 7);
            tile[t * 256 + slot * 8 + (c & 7)] = f2bf(v[k]);
        }
    }
    #pragma unroll
    for (int k = 0; k < 4; ++k) {
        ps[(lr * 4 + k) * 16 + w * 4 + lg] = s[k];
        pss[(lr * 4 + k) * 16 + w * 4 + lg] = ss[k];
    }
    __syncthreads();
    if (tid < 64) {
        float sum = 0.f, sq = 0.f;
        #pragma unroll
        for (int g = 0; g < 16; ++g) { sum += ps[tid * 16 + g]; sq += pss[tid * 16 + g]; }
        float m = sum * (1.f / 256.f);
        mbuf[(size_t)b * 8192 + t0 + tid] = m;
        rbuf[(size_t)b * 8192 + t0 + tid] = rsqrtf(sq * (1.f / 256.f) - m * m + 1e-5f);
    }
    int r = tid >> 2, q = tid & 3;
    size_t rowbase = ((size_t)b * 8192 + t0 + r) * 256;
    #pragma unroll
    for (int u = 0; u < 8; ++u) {
        int c0 = q * 64 + u * 8;
        int c8 = c0 >> 3;
        int slot = (c8 & 24) | ((c8 ^ r) & 7);
        short8 d = *(const short8*)&tile[r * 256 + slot * 8];
        *(short8*)&xt[rowbase + c0] = d;          // raw bf16(x) transposed
    }
}

// ---------------- 128x128-tile GEMM (Wm): LN-affine epilogue ----------------
// out = rs*(acc - m*colsum) + bmF   (A = raw xt)
template<int N, int K>
__global__ __launch_bounds__(256) void gemm_bt2(const u16* __restrict__ A,
                                                const u16* __restrict__ Bt,
                                                const float* __restrict__ bias,
                                                u16* __restrict__ outb,
                                                const float* __restrict__ mbuf,
                                                const float* __restrict__ rbuf,
                                                const float* __restrict__ colsum) {
    constexpr int NB = N / 128;
    int bid = blockIdx.x;
    int x8 = bid & 7;
    int rest = bid >> 3;
    int ni = rest % NB;
    int mi = (rest / NB) * 8 + x8;   // same-A siblings: 8 apart, same bid%8 -> same XCD
    int m0 = mi * 128, n0 = ni * 128;
    __shared__ u16 As[2][128 * 64];
    __shared__ u16 Bs[2][128 * 64];
    int tid = threadIdx.x, l = tid & 63, w = tid >> 6;
    int mrow = (w >> 1) * 64, ncol = (w & 1) * 64;
    int lr = l & 15, lg = l >> 4;
    f32x4 acc[4][4] = {};
    auto stage = [&](int buf, int k0) {
        #pragma unroll
        for (int p = 0; p < 4; ++p) {
            int cb = p * 256 + w * 64;
            int chunk = cb + l;
            int row = chunk >> 3, k8 = chunk & 7;
            int k8s = k8 ^ (row & 7);                 // pre-swizzled source
            lds_load16(A  + (size_t)(m0 + row) * K + k0 + k8s * 8, &As[buf][cb * 8]);
            lds_load16(Bt + (size_t)(n0 + row) * K + k0 + k8s * 8, &Bs[buf][cb * 8]);
        }
    };
    stage(0, 0);
    __syncthreads();
    constexpr int NT = K / 64;
    int buf = 0;
    for (int t = 0; t < NT; ++t) {
        if (t + 1 < NT) stage(buf ^ 1, (t + 1) * 64);   // issue next tile BEFORE compute
        __builtin_amdgcn_s_setprio(1);
        #pragma unroll
        for (int kk = 0; kk < 64; kk += 32) {
            short8 a[4], bfr[4];
            #pragma unroll
            for (int i = 0; i < 4; ++i) {
                int r = mrow + i * 16 + lr;
                a[i] = *(const short8*)&As[buf][r * 64 + ((((kk >> 3) + lg) ^ (r & 7)) << 3)];
            }
            #pragma unroll
            for (int j = 0; j < 4; ++j) {
                int r = ncol + j * 16 + lr;
                bfr[j] = *(const short8*)&Bs[buf][r * 64 + ((((kk >> 3) + lg) ^ (r & 7)) << 3)];
            }
            #pragma unroll
            for (int i = 0; i < 4; ++i)
                #pragma unroll
                for (int j = 0; j < 4; ++j)
                    acc[i][j] = __builtin_amdgcn_mfma_f32_16x16x32_bf16(a[i], bfr[j], acc[i][j], 0, 0, 0);
        }
        __builtin_amdgcn_s_setprio(0);
        __syncthreads();
        buf ^= 1;
    }
    #pragma unroll
    for (int i = 0; i < 4; ++i) {
        int row0 = m0 + mrow + i * 16 + lg * 4;
        f32x4 mv = *(const f32x4*)&mbuf[row0];
        f32x4 rv = *(const f32x4*)&rbuf[row0];
        #pragma unroll
        for (int j = 0; j < 4; ++j) {
            int col = n0 + ncol + j * 16 + lr;
            float bv = bias[col];
            float cs = colsum[col];
            f32x4 v = acc[i][j];
            #pragma unroll
            for (int r = 0; r < 4; ++r)
                outb[(size_t)(row0 + r) * N + col] =
                    f2bf(rv[r] * (v[r] - mv[r] * cs) + bv);
        }
    }
}

// ---------------- fused Wp-GEMM + LN2 + FFN: one 128-row tile per block ----------------
// phase 1: outb = att @ WpT^T + bp + xt  (tile 128x256 full width, written to global)
// phase 2: out = outb + gelu(ln2(outb) @ W1g + b1F) @ W2 + bf2 (v7b schedule)
__global__ __launch_bounds__(1024, 1) void wp_ffn(const u16* __restrict__ att,
                                                  const u16* __restrict__ WpT,
                                                  const float* __restrict__ bp,
                                                  const u16* __restrict__ xt,
                                                  const u16* __restrict__ W1g,
                                                  const float* __restrict__ b1F,
                                                  const u16* __restrict__ W2T,
                                                  const float* __restrict__ bf2v,
                                                  u16* __restrict__ outb,
                                                  float* __restrict__ out) {
    __shared__ u16 smem[73728];   // 144KB, re-purposed across phases
    int bid = blockIdx.x;
    int m0 = bid * 128;
    int tid = threadIdx.x, l = tid & 63, w = tid >> 6;   // w in [0,16)
    int lr = l & 15, lg = l >> 4;

    // LDS region accessors (computed per use; no generic-pointer static init)
    #define ASP(buf) (&smem[(buf) * 8192])
    #define BSP(buf) (&smem[16384 + (buf) * 16384])
    #define W1C(buf) (&smem[(buf) * 16384])
    #define W2C(buf) (&smem[32768 + (buf) * 16384])
    #define HBUF     (&smem[65536])

    // ---------- phase 1: Wp GEMM (128 rows x 256 cols, K=256) ----------
    {
        int wmP = w >> 2, wnP = w & 3;                  // wave = 32 rows x 64 cols
        f32x4 acc[2][4] = {};
        auto stageP = [&](int buf, int k0) {
            {   // A: 1024 chunks of 16B
                int chunk = tid;
                int row = chunk >> 3, k8 = chunk & 7;
                int k8s = k8 ^ (row & 7);
                lds_load16(att + (size_t)(m0 + row) * 256 + k0 + k8s * 8, ASP(buf) + chunk * 8);
            }
            #pragma unroll
            for (int p = 0; p < 2; ++p) {   // B: 2048 chunks
                int chunk = p * 1024 + tid;
                int row = chunk >> 3, k8 = chunk & 7;
                int k8s = k8 ^ (row & 7);
                lds_load16(WpT + (size_t)row * 256 + k0 + k8s * 8, BSP(buf) + chunk * 8);
            }
        };
        stageP(0, 0);
        __syncthreads();
        int buf = 0;
        for (int t = 0; t < 4; ++t) {
            if (t < 3) stageP(buf ^ 1, (t + 1) * 64);
            __builtin_amdgcn_s_setprio(1);
            #pragma unroll
            for (int kk = 0; kk < 64; kk += 32) {
                short8 a[2], bfr[4];
                #pragma unroll
                for (int i = 0; i < 2; ++i) {
                    int r = wmP * 32 + i * 16 + lr;
                    a[i] = *(const short8*)(ASP(buf) + r * 64 + ((((kk >> 3) + lg) ^ (r & 7)) << 3));
                }
                #pragma unroll
                for (int j = 0; j < 4; ++j) {
                    int n = wnP * 64 + j * 16 + lr;
                    bfr[j] = *(const short8*)(BSP(buf) + n * 64 + ((((kk >> 3) + lg) ^ (n & 7)) << 3));
                }
                #pragma unroll
                for (int i = 0; i < 2; ++i)
                    #pragma unroll
                    for (int j = 0; j < 4; ++j)
                        acc[i][j] = __builtin_amdgcn_mfma_f32_16x16x32_bf16(a[i], bfr[j], acc[i][j], 0, 0, 0);
            }
            __builtin_amdgcn_s_setprio(0);
            __syncthreads();
            buf ^= 1;
        }
        // epilogue: + bp + skip(xt) -> outb (global bf16)
        #pragma unroll
        for (int i = 0; i < 2; ++i) {
            int row0 = m0 + wmP * 32 + i * 16 + lg * 4;
            #pragma unroll
            for (int j = 0; j < 4; ++j) {
                int col = wnP * 64 + j * 16 + lr;
                float bv = bp[col];
                f32x4 v = acc[i][j];
                #pragma unroll
                for (int r = 0; r < 4; ++r)
                    outb[(size_t)(row0 + r) * 256 + col] =
                        f2bf(v[r] + bv + bf2f(xt[(size_t)(row0 + r) * 256 + col]));
            }
        }
    }
    __syncthreads();   // vmcnt(0) drain: outb tile visible; LDS reuse fence

    // ---------- phase 2: FFN (v7b) ----------
    int wm1 = w >> 1, wn1 = w & 1;     // GEMM1: 8 row-groups x 2 col-groups
    int wm2 = w >> 2, wn2 = w & 3;     // GEMM2: 4 row-groups x 4 col-groups

    // phase A: load 16 rows (L2-hot, just written), LN2 stats, normalize into a_reg
    short8 a_reg[8];
    {
        size_t base = (size_t)(m0 + wm1 * 16 + lr) * 256 + lg * 8;
        float s = 0.f, ss = 0.f;
        #pragma unroll
        for (int ks = 0; ks < 8; ++ks) {
            short8 rv = *(const short8*)&outb[base + ks * 32];
            a_reg[ks] = rv;
            #pragma unroll
            for (int e = 0; e < 8; ++e) { float v = bf2f_s(rv[e]); s += v; ss += v * v; }
        }
        s += __shfl_xor(s, 16); ss += __shfl_xor(ss, 16);
        s += __shfl_xor(s, 32); ss += __shfl_xor(ss, 32);
        float m = s * (1.f / 256.f);
        float rs = rsqrtf(ss * (1.f / 256.f) - m * m + 1e-5f);
        #pragma unroll
        for (int ks = 0; ks < 8; ++ks) {
            short8 rv = a_reg[ks], ov;
            #pragma unroll
            for (int e = 0; e < 8; ++e) ov[e] = (short)f2bf((bf2f_s(rv[e]) - m) * rs);
            a_reg[ks] = ov;
        }
    }

    auto stageW1 = [&](int buf, int c) {      // 2048 16B-chunks by 1024 threads
        #pragma unroll
        for (int p = 0; p < 2; ++p) {
            int cb = p * 1024 + w * 64;
            int chunk = cb + l;
            int row = chunk >> 5, sl = chunk & 31;
            int sl2 = (sl & 24) | ((sl ^ row) & 7);
            lds_load16(W1g + (size_t)(c * 64 + row) * 256 + sl2 * 8, W1C(buf) + cb * 8);
        }
    };
    auto stageW2 = [&](int buf, int c) {
        #pragma unroll
        for (int p = 0; p < 2; ++p) {
            int cb = p * 1024 + w * 64;
            int chunk = cb + l;
            int row = chunk >> 3, sl = chunk & 7;
            int sl2 = sl ^ (row & 7);
            lds_load16(W2T + (size_t)row * 1024 + c * 64 + sl2 * 8, W2C(buf) + cb * 8);
        }
    };
    stageW1(0, 0); stageW2(0, 0);
    f32x4 acc2[2][4] = {};
    __syncthreads();   // prologue drain: chunk-0 weights resident

    for (int c = 0; c < 16; ++c) {
        int buf = c & 1;
        // GEMM1 (swapped): lane holds h[row = wm1*16+lr][col = wn1*32 + nt*16 + lg*4 + r]
        f32x4 acc1[2] = {};
        __builtin_amdgcn_s_setprio(1);
        #pragma unroll
        for (int ks = 0; ks < 8; ++ks) {
            short8 wf[2];
            #pragma unroll
            for (int nt = 0; nt < 2; ++nt) {
                int n = wn1 * 32 + nt * 16 + lr;
                int sl = ks * 4 + lg;
                int sl2 = (sl & 24) | ((sl ^ n) & 7);
                wf[nt] = *(const short8*)(W1C(buf) + n * 256 + sl2 * 8);
            }
            #pragma unroll
            for (int nt = 0; nt < 2; ++nt)
                acc1[nt] = __builtin_amdgcn_mfma_f32_16x16x32_bf16(
                    wf[nt], a_reg[ks], acc1[nt], 0, 0, 0);
        }
        __builtin_amdgcn_s_setprio(0);
        // stage NEXT chunk (after GEMM1's read burst; drain distance = gelu+GEMM2)
        if (c < 15) { stageW1(buf ^ 1, c + 1); stageW2(buf ^ 1, c + 1); }
        // gelu + cvt_pk pack + hbuf b64 write (swizzled)
        #pragma unroll
        for (int nt = 0; nt < 2; ++nt) {
            int colb = wn1 * 32 + nt * 16 + lg * 4;
            int row = wm1 * 16 + lr;
            f32x4 bv4 = *(const f32x4*)&b1F[c * 64 + colb];
            float g0 = gelu_fast(acc1[nt][0] + bv4[0]);
            float g1v = gelu_fast(acc1[nt][1] + bv4[1]);
            float g2v = gelu_fast(acc1[nt][2] + bv4[2]);
            float g3v = gelu_fast(acc1[nt][3] + bv4[3]);
            uint2 dd;
            asm("v_cvt_pk_bf16_f32 %0, %1, %2" : "=v"(dd.x) : "v"(g0), "v"(g1v));
            asm("v_cvt_pk_bf16_f32 %0, %1, %2" : "=v"(dd.y) : "v"(g2v), "v"(g3v));
            int sl2 = (colb >> 3) ^ (row & 7);
            *(uint2*)(HBUF + row * 64 + sl2 * 8 + (colb & 7)) = dd;
        }
        // mid barrier: lgkm-only; staged vmem stays in flight
        asm volatile("s_waitcnt lgkmcnt(0)" ::: "memory");
        __builtin_amdgcn_s_barrier();
        __builtin_amdgcn_sched_barrier(0);
        // GEMM2: acc2[mt][nt] += h(32x64slice) @ W2c^T
        __builtin_amdgcn_s_setprio(1);
        #pragma unroll
        for (int ks = 0; ks < 2; ++ks) {
            short8 hf[2], w2f[4];
            #pragma unroll
            for (int mt = 0; mt < 2; ++mt) {
                int row = wm2 * 32 + mt * 16 + lr;
                int sl2 = (ks * 4 + lg) ^ (row & 7);
                hf[mt] = *(const short8*)(HBUF + row * 64 + sl2 * 8);
            }
            #pragma unroll
            for (int nt = 0; nt < 4; ++nt) {
                int n = wn2 * 64 + nt * 16 + lr;
                int sl2 = (ks * 4 + lg) ^ (n & 7);
                w2f[nt] = *(const short8*)(W2C(buf) + n * 64 + sl2 * 8);
            }
            #pragma unroll
            for (int mt = 0; mt < 2; ++mt)
                #pragma unroll
                for (int nt = 0; nt < 4; ++nt)
                    acc2[mt][nt] = __builtin_amdgcn_mfma_f32_16x16x32_bf16(
                        hf[mt], w2f[nt], acc2[mt][nt], 0, 0, 0);
        }
        __builtin_amdgcn_s_setprio(0);
        __syncthreads();   // end-of-chunk drain (stage loads issued well before)
    }
    // epilogue: + bias + resid(outb, L2-hot), store fp32 transposed (B,C,T)
    int bb_ = m0 >> 13;
    int tb = m0 & 8191;
    #pragma unroll
    for (int mt = 0; mt < 2; ++mt) {
        int row0 = wm2 * 32 + mt * 16 + lg * 4;
        #pragma unroll
        for (int nt = 0; nt < 4; ++nt) {
            int col = wn2 * 64 + nt * 16 + lr;
            float bv = bf2v[col];
            f32x4 o;
            #pragma unroll
            for (int r = 0; r < 4; ++r)
                o[r] = acc2[mt][nt][r] + bv + bf2f(outb[(size_t)(m0 + row0 + r) * 256 + col]);
            *(f32x4*)&out[((size_t)bb_ * 256 + col) * 8192 + tb + row0] = o;
        }
    }
    #undef ASP
    #undef BSP
    #undef W1C
    #undef W2C
    #undef HBUF
}

// ---------------- mixer: conv (path 0) + attn type1 (path 1) + attn type2 (path 2) ----
__global__ __launch_bounds__(256) void mixer_kernel(const u16* __restrict__ f,
                                                    const u16* __restrict__ WtC,
                                                    const float* __restrict__ bc,
                                                    const float* __restrict__ tab1,
                                                    const float* __restrict__ tab2,
                                                    u16* __restrict__ att) {
    __shared__ u16 smem[25600];
    __shared__ float stab[60];
    int bid = blockIdx.x;
    int path = bid % 3;
    int inner = bid / 3;
    int b = inner >> 7;
    int tid = threadIdx.x, l = tid & 63, w = tid >> 6;

    if (path == 0) {
        u16* fs = smem;              // 72*128
        u16* wt = smem + 9216;       // 128*128
        int t0 = (inner & 127) << 6;
        // wt via global_load_lds: linear dest chunk c = tid + k*256, pre-swizzled source
        #pragma unroll
        for (int k = 0; k < 8; ++k) {
            int c = tid + k * 256;
            int row = c >> 4, sl = c & 15;
            int c8s = (sl & 8) | ((sl ^ row) & 7);     // involution: src chunk whose swz = sl
            lds_load16(WtC + row * 128 + c8s * 8, &wt[c * 8]);
        }
        for (int c = tid; c < 72 * 16; c += 256) {
            int rrow = c >> 4, c8 = c & 15;
            int t = t0 - 3 + rrow;
            uint4 v = {0u, 0u, 0u, 0u};
            if (t >= 0 && t < 8192)
                v = *(const uint4*)&f[((size_t)b * 8192 + t) * 512 + c8 * 8];
            int slot = (c8 & 8) | ((c8 ^ rrow) & 7);
            *(uint4*)&fs[rrow * 128 + slot * 8] = v;
        }
        __syncthreads();
        int wr = w >> 1, wc = w & 1;
        int lr = l & 15, lg = l >> 4;
        f32x4 acc[2][4] = {};
        #pragma unroll
        for (int kk = 0; kk < 4; ++kk) {
            int kp = kk * 32 + lg * 8;
            int tap = kp >> 4, ci = kp & 15;
            #pragma unroll
            for (int i = 0; i < 2; ++i) {
                int trow = wr * 32 + i * 16 + lr;
                #pragma unroll
                for (int g = 0; g < 4; ++g) {
                    int ra = trow + tap;
                    int ea = (wc * 4 + g) * 2 + (ci >> 3);
                    short8 a = *(const short8*)&fs[ra * 128 + (((ea & 8) | ((ea ^ ra) & 7)) << 3)];
                    int nb = (wc * 4 + g) * 16 + lr;
                    int eb = kp >> 3;
                    short8 bfr = *(const short8*)&wt[nb * 128 + (((eb & 8) | ((eb ^ nb) & 7)) << 3)];
                    acc[i][g] = __builtin_amdgcn_mfma_f32_16x16x32_bf16(a, bfr, acc[i][g], 0, 0, 0);
                }
            }
        }
        #pragma unroll
        for (int i = 0; i < 2; ++i) {
            int trow = wr * 32 + i * 16 + lg * 4;
            #pragma unroll
            for (int g = 0; g < 4; ++g) {
                int co = (wc * 4 + g) * 16 + lr;
                float bv = bc[co];
                #pragma unroll
                for (int r = 0; r < 4; ++r) {
                    int t = t0 + trow + r;
                    att[((size_t)b * 8192 + t) * 256 + co] = f2bf(acc[i][g][r] + bv);
                }
            }
        }
    } else {
        u16* qkv = smem;             // 64*200
        const int QBASE = (path == 1) ? 128 : 320;
        const int OBASE = (path == 1) ? 128 : 192;
        const float* tab = (path == 1) ? tab1 : tab2;
        int j0 = (inner & 127) << 3;
        if (tid < 60) stab[tid] = tab[tid];
        for (int c = tid; c < 64 * 24; c += 256) {
            int ridx = c / 24, off = (c % 24) << 3;
            int wl = ridx >> 3, n = ridx & 7;
            int t = (path == 1) ? ((j0 + wl) * 8 + n) : (n * 1024 + j0 + wl);
            *(uint4*)&qkv[ridx * 200 + off] = *(const uint4*)&f[((size_t)b * 8192 + t) * 512 + QBASE + off];
        }
        __syncthreads();
        int wl = tid >> 5, h = (tid >> 3) & 3, n = tid & 7;
        const u16* qr = &qkv[(wl * 8 + n) * 200 + h * 16];
        float q[16];
        {
            short8 q0 = *(const short8*)qr, q1 = *(const short8*)(qr + 8);
            #pragma unroll
            for (int d = 0; d < 8; ++d) { q[d] = bf2f_s(q0[d]); q[d + 8] = bf2f_s(q1[d]); }
        }
        float s[8];
        #pragma unroll
        for (int m = 0; m < 8; ++m) {
            const u16* kr = &qkv[(wl * 8 + m) * 200 + 64 + h * 16];
            short8 k0 = *(const short8*)kr, k1 = *(const short8*)(kr + 8);
            float a = 0.f;
            #pragma unroll
            for (int d = 0; d < 8; ++d) a += q[d] * bf2f_s(k0[d]) + q[d + 8] * bf2f_s(k1[d]);
            s[m] = 0.5f * a + stab[(n - m + 7) * 4 + h];
        }
        float mx = s[0];
        #pragma unroll
        for (int m = 1; m < 8; ++m) mx = fmaxf(mx, s[m]);
        float sum = 0.f;
        #pragma unroll
        for (int m = 0; m < 8; ++m) { s[m] = __expf(s[m] - mx); sum += s[m]; }
        float rinv = 1.f / sum;
        float o[16] = {};
        #pragma unroll
        for (int m = 0; m < 8; ++m) {
            float p = s[m] * rinv;
            const u16* vr = &qkv[(wl * 8 + m) * 200 + 128 + h * 16];
            short8 v0 = *(const short8*)vr, v1 = *(const short8*)(vr + 8);
            #pragma unroll
            for (int d = 0; d < 8; ++d) { o[d] += p * bf2f_s(v0[d]); o[d + 8] += p * bf2f_s(v1[d]); }
        }
        int t = (path == 1) ? ((j0 + wl) * 8 + n) : (n * 1024 + j0 + wl);
        short8 o0, o1;
        #pragma unroll
        for (int d = 0; d < 8; ++d) { o0[d] = (short)f2bf(o[d]); o1[d] = (short)f2bf(o[d + 8]); }
        u16* op = &att[((size_t)b * 8192 + t) * 256 + OBASE + h * 16];
        *(short8*)op = o0; *(short8*)(op + 8) = o1;
    }
}

extern "C" void kernel_launch(void* const* d_in, const int* in_sizes, int n_in,
                              void* d_out, int out_size, void* d_ws, size_t ws_size,
                              hipStream_t stream) {
    const float* x    = (const float*)d_in[0];
    const float* g1   = (const float*)d_in[1];
    const float* b1   = (const float*)d_in[2];
    const float* Wm   = (const float*)d_in[3];
    const float* bm   = (const float*)d_in[4];
    const float* Wc   = (const float*)d_in[5];
    const float* bc   = (const float*)d_in[6];
    const float* tab1 = (const float*)d_in[7];
    const float* tab2 = (const float*)d_in[8];
    const float* Wp   = (const float*)d_in[9];
    const float* bp   = (const float*)d_in[10];
    const float* g2   = (const float*)d_in[11];
    const float* b2   = (const float*)d_in[12];
    const float* W1   = (const float*)d_in[13];
    const float* bf1  = (const float*)d_in[14];
    const float* W2   = (const float*)d_in[15];
    const float* bf2  = (const float*)d_in[16];
    float* out = (float*)d_out;

    char* ws = (char*)d_ws;
    // layout: f 134MB | att 67MB | outb 67MB | (unused) | xt 67MB | weights+stats ~3.5MB
    u16* f    = (u16*)(ws);
    u16* att  = (u16*)(ws + 134217728);
    u16* outb = (u16*)(ws + 201326592);
    u16* xt   = (u16*)(ws + 335544320);
    char* wb = ws + 402653184;
    u16* WmT    = (u16*)wb;                    // 262144 B
    u16* WpT    = (u16*)(wb + 262144);         // 131072 B
    u16* W1T    = (u16*)(wb + 393216);         // 524288 B
    u16* W2T    = (u16*)(wb + 917504);         // 524288 B
    u16* WtC    = (u16*)(wb + 1441792);        // 32768 B
    float* bmF  = (float*)(wb + 1474560);      // 2048 B
    float* b1F  = (float*)(wb + 1476608);      // 4096 B
    float* cs1  = (float*)(wb + 1480704);      // 2048 B  (colsum of g1*Wm)
    float* mbuf = (float*)(wb + 1482752);      // 524288 B
    float* rbuf = (float*)(wb + 2007040);      // 524288 B

    prep_weights<<<512, 256, 0, stream>>>(Wm, Wp, W1, W2, Wc, g1, b1, g2, b2, bm, bf1,
                                          WmT, WpT, W1T, W2T, WtC, bmF, b1F, cs1);
    ln1_kernel<<<Bb * (Tt / 64), 256, 0, stream>>>(x, xt, mbuf, rbuf);
    gemm_bt2<512, 256><<<(M_TOT / 128) * 4, 256, 0, stream>>>(xt, WmT, bmF, f, mbuf, rbuf, cs1);
    mixer_kernel<<<3 * Bb * 128, 256, 0, stream>>>(f, WtC, bc, tab1, tab2, att);
    wp_ffn<<<M_TOT / 128, 1024, 0, stream>>>(att, WpT, bp, xt, W1T, b1F, W2T, bf2, outb, out);
}

// Round 18
// 462.333 us; speedup vs baseline: 1.0450x; 1.0450x over previous
//
#include <hip/hip_runtime.h>
#include <hip/hip_bf16.h>

#define DI __device__ __forceinline__

typedef unsigned short u16;
typedef __attribute__((ext_vector_type(4))) float f32x4;
typedef __attribute__((ext_vector_type(8))) short short8;
typedef __attribute__((ext_vector_type(4))) short short4v;

constexpr int Bb = 16, Tt = 8192;
constexpr int M_TOT = Bb * Tt; // 131072

static DI u16 f2bf(float f) {
    union { float f; unsigned u; } v; v.f = f;
    unsigned r = v.u + 0x7fffu + ((v.u >> 16) & 1u);
    return (u16)(r >> 16);
}
static DI float bf2f(u16 u) {
    union { unsigned u; float f; } v; v.u = ((unsigned)u) << 16;
    return v.f;
}
static DI float bf2f_s(short s) { return bf2f((u16)s); }

static DI void lds_load16(const void* g, void* l) {
    __builtin_amdgcn_global_load_lds(
        (const __attribute__((address_space(1))) void*)g,
        (__attribute__((address_space(3))) void*)l, 16, 0, 0);
}

// tanh-approx gelu, exp2 with folded constants: |err| <= ~1e-3 abs
static DI float gelu_fast(float x) {
    float x2 = x * x;
    float z2 = x * (2.30220723f + 0.10294515f * x2);  // 2*sqrt(2/pi)*log2e*(1+0.044715x^2)
    float e;
    asm("v_exp_f32 %0, %1" : "=v"(e) : "v"(z2));      // e = 2^z2 = e^{2z}
    float r = __builtin_amdgcn_rcpf(1.f + e);
    return x - x * r;                                  // x*e/(1+e)
}

// ---------------- weight prep: transpose + bf16 + LN-fold + colsum ----------------
__global__ void prep_weights(const float* __restrict__ Wm, const float* __restrict__ Wp,
                             const float* __restrict__ W1, const float* __restrict__ W2,
                             const float* __restrict__ Wc,
                             const float* __restrict__ g1, const float* __restrict__ b1,
                             const float* __restrict__ g2, const float* __restrict__ b2,
                             const float* __restrict__ bm, const float* __restrict__ bf1,
                             u16* __restrict__ WmT, u16* __restrict__ WpT,
                             u16* __restrict__ W1T, u16* __restrict__ W2T,
                             u16* __restrict__ WtC,
                             float* __restrict__ bmF, float* __restrict__ b1F,
                             float* __restrict__ colsum) {
    int i = blockIdx.x * blockDim.x + threadIdx.x;
    int stride = gridDim.x * blockDim.x;
    for (int j = i; j < 512 * 256; j += stride) {       // WmT[n][k] = g1[k]*Wm[k][n]
        int n = j >> 8, k = j & 255;
        WmT[j] = f2bf(Wm[k * 512 + n] * g1[k]);
    }
    for (int j = i; j < 256 * 256; j += stride) {       // WpT
        int n = j >> 8, k = j & 255;
        WpT[j] = f2bf(Wp[k * 256 + n]);
    }
    for (int j = i; j < 1024 * 256; j += stride) {      // W1T[n][k] = g2[k]*W1[k][n]
        int n = j >> 8, k = j & 255;
        W1T[j] = f2bf(W1[k * 1024 + n] * g2[k]);
    }
    for (int j = i; j < 256 * 1024; j += stride) {      // W2T[n][k] = W2[k][n]
        int n = j >> 10, k = j & 1023;
        W2T[j] = f2bf(W2[k * 256 + n]);
    }
    for (int j = i; j < 128 * 128; j += stride) {       // conv weights: [co][k'=tap*16+ci]
        int co = j >> 7, kp = j & 127;
        int tap = kp >> 4, ci = kp & 15;
        float v = (tap < 7) ? Wc[(co * 16 + ci) * 7 + tap] : 0.f;
        WtC[j] = f2bf(v);
    }
    for (int n = i; n < 512; n += stride) {             // bmF = bm + b1 @ Wm ; colsum = g1 @ Wm col
        float s = bm[n], cs = 0.f;
        for (int k = 0; k < 256; ++k) {
            s += b1[k] * Wm[k * 512 + n];
            cs += g1[k] * Wm[k * 512 + n];
        }
        bmF[n] = s;
        colsum[n] = cs;
    }
    for (int n = i; n < 1024; n += stride) {            // b1F = bf1 + b2 @ W1
        float s = bf1[n];
        for (int k = 0; k < 256; ++k) s += b2[k] * W1[k * 1024 + n];
        b1F[n] = s;
    }
}

// ---------------- LN1-lite: transpose (B,C,T)->(B*T,C) bf16 + per-row (mean, rstd) ----
__global__ __launch_bounds__(256) void ln1_kernel(const float* __restrict__ x,
                                                  u16* __restrict__ xt,
                                                  float* __restrict__ mbuf,
                                                  float* __restrict__ rbuf) {
    __shared__ u16 tile[64 * 256];            // [t][c], XOR-swizzled in 16B slots
    __shared__ float ps[64 * 16], pss[64 * 16];
    int bidx = blockIdx.x;
    int b = bidx >> 7;
    int t0 = (bidx & 127) << 6;
    int tid = threadIdx.x, l = tid & 63, w = tid >> 6;
    int lr = l & 15, lg = l >> 4;
    float s[4] = {}, ss[4] = {};
    #pragma unroll 4
    for (int it = 0; it < 16; ++it) {
        int c = it * 16 + w * 4 + lg;
        f32x4 v = *(const f32x4*)&x[((size_t)b * 256 + c) * 8192 + t0 + lr * 4];
        #pragma unroll
        for (int k = 0; k < 4; ++k) {
            s[k] += v[k]; ss[k] += v[k] * v[k];
            int t = lr * 4 + k;
            int c8 = c >> 3;
            int slot = (c8 & 24) | ((c8 ^ t) & 7);
            tile[t * 256 + slot * 8 + (c & 7)] = f2bf(v[k]);
        }
    }
    #pragma unroll
    for (int k = 0; k < 4; ++k) {
        ps[(lr * 4 + k) * 16 + w * 4 + lg] = s[k];
        pss[(lr * 4 + k) * 16 + w * 4 + lg] = ss[k];
    }
    __syncthreads();
    if (tid < 64) {
        float sum = 0.f, sq = 0.f;
        #pragma unroll
        for (int g = 0; g < 16; ++g) { sum += ps[tid * 16 + g]; sq += pss[tid * 16 + g]; }
        float m = sum * (1.f / 256.f);
        mbuf[(size_t)b * 8192 + t0 + tid] = m;
        rbuf[(size_t)b * 8192 + t0 + tid] = rsqrtf(sq * (1.f / 256.f) - m * m + 1e-5f);
    }
    int r = tid >> 2, q = tid & 3;
    size_t rowbase = ((size_t)b * 8192 + t0 + r) * 256;
    #pragma unroll
    for (int u = 0; u < 8; ++u) {
        int c0 = q * 64 + u * 8;
        int c8 = c0 >> 3;
        int slot = (c8 & 24) | ((c8 ^ r) & 7);
        short8 d = *(const short8*)&tile[r * 256 + slot * 8];
        *(short8*)&xt[rowbase + c0] = d;          // raw bf16(x) transposed
    }
}

// ---------------- 128x128-tile GEMM: dbuf LDS, T2 swizzle, XCD ordering ----------------
// EPI 0: LN-affine epilogue: out = rs*(acc - m*colsum) + bmF   (A = raw xt)
// EPI 1: +bias + bf16 skip -> bf16 (out_buf)
template<int EPI, int N, int K>
__global__ __launch_bounds__(256) void gemm_bt2(const u16* __restrict__ A,
                                                const u16* __restrict__ Bt,
                                                const float* __restrict__ bias,
                                                u16* __restrict__ outb,
                                                const u16* __restrict__ skipx,
                                                const float* __restrict__ mbuf,
                                                const float* __restrict__ rbuf,
                                                const float* __restrict__ colsum) {
    constexpr int NB = N / 128;
    int bid = blockIdx.x;
    int x8 = bid & 7;
    int rest = bid >> 3;
    int ni = rest % NB;
    int mi = (rest / NB) * 8 + x8;   // same-A siblings: 8 apart, same bid%8 -> same XCD
    int m0 = mi * 128, n0 = ni * 128;
    __shared__ u16 As[2][128 * 64];
    __shared__ u16 Bs[2][128 * 64];
    int tid = threadIdx.x, l = tid & 63, w = tid >> 6;
    int mrow = (w >> 1) * 64, ncol = (w & 1) * 64;
    int lr = l & 15, lg = l >> 4;
    f32x4 acc[4][4] = {};
    auto stage = [&](int buf, int k0) {
        #pragma unroll
        for (int p = 0; p < 4; ++p) {
            int cb = p * 256 + w * 64;
            int chunk = cb + l;
            int row = chunk >> 3, k8 = chunk & 7;
            int k8s = k8 ^ (row & 7);                 // pre-swizzled source
            lds_load16(A  + (size_t)(m0 + row) * K + k0 + k8s * 8, &As[buf][cb * 8]);
            lds_load16(Bt + (size_t)(n0 + row) * K + k0 + k8s * 8, &Bs[buf][cb * 8]);
        }
    };
    stage(0, 0);
    __syncthreads();
    constexpr int NT = K / 64;
    int buf = 0;
    for (int t = 0; t < NT; ++t) {
        if (t + 1 < NT) stage(buf ^ 1, (t + 1) * 64);   // issue next tile BEFORE compute
        __builtin_amdgcn_s_setprio(1);
        #pragma unroll
        for (int kk = 0; kk < 64; kk += 32) {
            short8 a[4], bfr[4];
            #pragma unroll
            for (int i = 0; i < 4; ++i) {
                int r = mrow + i * 16 + lr;
                a[i] = *(const short8*)&As[buf][r * 64 + ((((kk >> 3) + lg) ^ (r & 7)) << 3)];
            }
            #pragma unroll
            for (int j = 0; j < 4; ++j) {
                int r = ncol + j * 16 + lr;
                bfr[j] = *(const short8*)&Bs[buf][r * 64 + ((((kk >> 3) + lg) ^ (r & 7)) << 3)];
            }
            #pragma unroll
            for (int i = 0; i < 4; ++i)
                #pragma unroll
                for (int j = 0; j < 4; ++j)
                    acc[i][j] = __builtin_amdgcn_mfma_f32_16x16x32_bf16(a[i], bfr[j], acc[i][j], 0, 0, 0);
        }
        __builtin_amdgcn_s_setprio(0);
        __syncthreads();
        buf ^= 1;
    }
    #pragma unroll
    for (int i = 0; i < 4; ++i) {
        int row0 = m0 + mrow + i * 16 + lg * 4;
        f32x4 mv, rv;
        if constexpr (EPI == 0) {
            mv = *(const f32x4*)&mbuf[row0];
            rv = *(const f32x4*)&rbuf[row0];
        }
        #pragma unroll
        for (int j = 0; j < 4; ++j) {
            int col = n0 + ncol + j * 16 + lr;
            float bv = bias[col];
            f32x4 v = acc[i][j];
            if constexpr (EPI == 0) {
                float cs = colsum[col];
                #pragma unroll
                for (int r = 0; r < 4; ++r)
                    outb[(size_t)(row0 + r) * N + col] =
                        f2bf(rv[r] * (v[r] - mv[r] * cs) + bv);
            } else {
                #pragma unroll
                for (int r = 0; r < 4; ++r)
                    outb[(size_t)(row0 + r) * N + col] =
                        f2bf(v[r] + bv + bf2f(skipx[(size_t)(row0 + r) * 256 + col]));
            }
        }
    }
}

// ---------------- fused LN2+FFN v7b (best): phase A first; stage after GEMM1 ----
__global__ __launch_bounds__(1024, 1) void ffn_fused7(const u16* __restrict__ outb,
                                                      const u16* __restrict__ W1g,
                                                      const float* __restrict__ b1F,
                                                      const u16* __restrict__ W2T,
                                                      const float* __restrict__ bf2v,
                                                      float* __restrict__ out) {
    __shared__ u16 W1c[2][64 * 256];   // 32KB x2
    __shared__ u16 W2c[2][256 * 64];   // 32KB x2
    __shared__ u16 hbuf[128 * 64];     // 16KB  -> 144KB
    int bid = blockIdx.x;
    int m0 = bid * 128;
    int tid = threadIdx.x, l = tid & 63, w = tid >> 6;   // w in [0,16)
    int lr = l & 15, lg = l >> 4;
    int wm1 = w >> 1, wn1 = w & 1;     // GEMM1: 8 row-groups x 2 col-groups
    int wm2 = w >> 2, wn2 = w & 3;     // GEMM2: 4 row-groups x 4 col-groups

    // ---- phase A: load 16 rows, LN2 stats, normalize into a_reg ----
    short8 a_reg[8];
    {
        size_t base = (size_t)(m0 + wm1 * 16 + lr) * 256 + lg * 8;
        float s = 0.f, ss = 0.f;
        #pragma unroll
        for (int ks = 0; ks < 8; ++ks) {
            short8 rv = *(const short8*)&outb[base + ks * 32];
            a_reg[ks] = rv;
            #pragma unroll
            for (int e = 0; e < 8; ++e) { float v = bf2f_s(rv[e]); s += v; ss += v * v; }
        }
        s += __shfl_xor(s, 16); ss += __shfl_xor(ss, 16);
        s += __shfl_xor(s, 32); ss += __shfl_xor(ss, 32);
        float m = s * (1.f / 256.f);
        float rs = rsqrtf(ss * (1.f / 256.f) - m * m + 1e-5f);
        #pragma unroll
        for (int ks = 0; ks < 8; ++ks) {
            short8 rv = a_reg[ks], ov;
            #pragma unroll
            for (int e = 0; e < 8; ++e) ov[e] = (short)f2bf((bf2f_s(rv[e]) - m) * rs);
            a_reg[ks] = ov;
        }
    }

    auto stageW1 = [&](int buf, int c) {      // 2048 16B-chunks by 1024 threads
        #pragma unroll
        for (int p = 0; p < 2; ++p) {
            int cb = p * 1024 + w * 64;
            int chunk = cb + l;
            int row = chunk >> 5, sl = chunk & 31;
            int sl2 = (sl & 24) | ((sl ^ row) & 7);
            lds_load16(W1g + (size_t)(c * 64 + row) * 256 + sl2 * 8, &W1c[buf][cb * 8]);
        }
    };
    auto stageW2 = [&](int buf, int c) {
        #pragma unroll
        for (int p = 0; p < 2; ++p) {
            int cb = p * 1024 + w * 64;
            int chunk = cb + l;
            int row = chunk >> 3, sl = chunk & 7;
            int sl2 = sl ^ (row & 7);
            lds_load16(W2T + (size_t)row * 1024 + c * 64 + sl2 * 8, &W2c[buf][cb * 8]);
        }
    };
    stageW1(0, 0); stageW2(0, 0);
    f32x4 acc2[2][4] = {};
    __syncthreads();   // prologue drain: chunk-0 weights resident

    for (int c = 0; c < 16; ++c) {
        int buf = c & 1;
        // GEMM1 (swapped): lane holds h[row = wm1*16+lr][col = wn1*32 + nt*16 + lg*4 + r]
        f32x4 acc1[2] = {};
        __builtin_amdgcn_s_setprio(1);
        #pragma unroll
        for (int ks = 0; ks < 8; ++ks) {
            short8 wf[2];
            #pragma unroll
            for (int nt = 0; nt < 2; ++nt) {
                int n = wn1 * 32 + nt * 16 + lr;
                int sl = ks * 4 + lg;
                int sl2 = (sl & 24) | ((sl ^ n) & 7);
                wf[nt] = *(const short8*)&W1c[buf][n * 256 + sl2 * 8];
            }
            #pragma unroll
            for (int nt = 0; nt < 2; ++nt)
                acc1[nt] = __builtin_amdgcn_mfma_f32_16x16x32_bf16(
                    wf[nt], a_reg[ks], acc1[nt], 0, 0, 0);
        }
        __builtin_amdgcn_s_setprio(0);
        // stage NEXT chunk (after GEMM1's read burst; drain distance = gelu+GEMM2)
        if (c < 15) { stageW1(buf ^ 1, c + 1); stageW2(buf ^ 1, c + 1); }
        // gelu + cvt_pk pack + hbuf b64 write (swizzled)
        #pragma unroll
        for (int nt = 0; nt < 2; ++nt) {
            int colb = wn1 * 32 + nt * 16 + lg * 4;
            int row = wm1 * 16 + lr;
            f32x4 bv4 = *(const f32x4*)&b1F[c * 64 + colb];
            float g0 = gelu_fast(acc1[nt][0] + bv4[0]);
            float g1v = gelu_fast(acc1[nt][1] + bv4[1]);
            float g2v = gelu_fast(acc1[nt][2] + bv4[2]);
            float g3v = gelu_fast(acc1[nt][3] + bv4[3]);
            uint2 dd;
            asm("v_cvt_pk_bf16_f32 %0, %1, %2" : "=v"(dd.x) : "v"(g0), "v"(g1v));
            asm("v_cvt_pk_bf16_f32 %0, %1, %2" : "=v"(dd.y) : "v"(g2v), "v"(g3v));
            int sl2 = (colb >> 3) ^ (row & 7);
            *(uint2*)&hbuf[row * 64 + sl2 * 8 + (colb & 7)] = dd;
        }
        // mid barrier: lgkm-only; staged vmem stays in flight
        asm volatile("s_waitcnt lgkmcnt(0)" ::: "memory");
        __builtin_amdgcn_s_barrier();
        __builtin_amdgcn_sched_barrier(0);
        // GEMM2: acc2[mt][nt] += h(32x64slice) @ W2c^T
        __builtin_amdgcn_s_setprio(1);
        #pragma unroll
        for (int ks = 0; ks < 2; ++ks) {
            short8 hf[2], w2f[4];
            #pragma unroll
            for (int mt = 0; mt < 2; ++mt) {
                int row = wm2 * 32 + mt * 16 + lr;
                int sl2 = (ks * 4 + lg) ^ (row & 7);
                hf[mt] = *(const short8*)&hbuf[row * 64 + sl2 * 8];
            }
            #pragma unroll
            for (int nt = 0; nt < 4; ++nt) {
                int n = wn2 * 64 + nt * 16 + lr;
                int sl2 = (ks * 4 + lg) ^ (n & 7);
                w2f[nt] = *(const short8*)&W2c[buf][n * 64 + sl2 * 8];
            }
            #pragma unroll
            for (int mt = 0; mt < 2; ++mt)
                #pragma unroll
                for (int nt = 0; nt < 4; ++nt)
                    acc2[mt][nt] = __builtin_amdgcn_mfma_f32_16x16x32_bf16(
                        hf[mt], w2f[nt], acc2[mt][nt], 0, 0, 0);
        }
        __builtin_amdgcn_s_setprio(0);
        __syncthreads();   // end-of-chunk drain (stage loads issued well before)
    }
    // epilogue: + bias + resid(outb), store fp32 transposed (B,C,T)
    int bb_ = m0 >> 13;
    int tb = m0 & 8191;
    #pragma unroll
    for (int mt = 0; mt < 2; ++mt) {
        int row0 = wm2 * 32 + mt * 16 + lg * 4;
        #pragma unroll
        for (int nt = 0; nt < 4; ++nt) {
            int col = wn2 * 64 + nt * 16 + lr;
            float bv = bf2v[col];
            f32x4 o;
            #pragma unroll
            for (int r = 0; r < 4; ++r)
                o[r] = acc2[mt][nt][r] + bv + bf2f(outb[(size_t)(m0 + row0 + r) * 256 + col]);
            *(f32x4*)&out[((size_t)bb_ * 256 + col) * 8192 + tb + row0] = o;
        }
    }
}

// ---------------- mixer: conv (path 0) + attn type1 (path 1) + attn type2 (path 2) ----
__global__ __launch_bounds__(256) void mixer_kernel(const u16* __restrict__ f,
                                                    const u16* __restrict__ WtC,
                                                    const float* __restrict__ bc,
                                                    const float* __restrict__ tab1,
                                                    const float* __restrict__ tab2,
                                                    u16* __restrict__ att) {
    __shared__ u16 smem[25600];
    __shared__ float stab[60];
    int bid = blockIdx.x;
    int path = bid % 3;
    int inner = bid / 3;
    int b = inner >> 7;
    int tid = threadIdx.x, l = tid & 63, w = tid >> 6;

    if (path == 0) {
        u16* fs = smem;              // 72*128
        u16* wt = smem + 9216;       // 128*128
        int t0 = (inner & 127) << 6;
        // wt via global_load_lds: linear dest chunk c = tid + k*256, pre-swizzled source
        #pragma unroll
        for (int k = 0; k < 8; ++k) {
            int c = tid + k * 256;
            int row = c >> 4, sl = c & 15;
            int c8s = (sl & 8) | ((sl ^ row) & 7);     // involution: src chunk whose swz = sl
            lds_load16(WtC + row * 128 + c8s * 8, &wt[c * 8]);
        }
        for (int c = tid; c < 72 * 16; c += 256) {
            int rrow = c >> 4, c8 = c & 15;
            int t = t0 - 3 + rrow;
            uint4 v = {0u, 0u, 0u, 0u};
            if (t >= 0 && t < 8192)
                v = *(const uint4*)&f[((size_t)b * 8192 + t) * 512 + c8 * 8];
            int slot = (c8 & 8) | ((c8 ^ rrow) & 7);
            *(uint4*)&fs[rrow * 128 + slot * 8] = v;
        }
        __syncthreads();
        int wr = w >> 1, wc = w & 1;
        int lr = l & 15, lg = l >> 4;
        f32x4 acc[2][4] = {};
        #pragma unroll
        for (int kk = 0; kk < 4; ++kk) {
            int kp = kk * 32 + lg * 8;
            int tap = kp >> 4, ci = kp & 15;
            #pragma unroll
            for (int i = 0; i < 2; ++i) {
                int trow = wr * 32 + i * 16 + lr;
                #pragma unroll
                for (int g = 0; g < 4; ++g) {
                    int ra = trow + tap;
                    int ea = (wc * 4 + g) * 2 + (ci >> 3);
                    short8 a = *(const short8*)&fs[ra * 128 + (((ea & 8) | ((ea ^ ra) & 7)) << 3)];
                    int nb = (wc * 4 + g) * 16 + lr;
                    int eb = kp >> 3;
                    short8 bfr = *(const short8*)&wt[nb * 128 + (((eb & 8) | ((eb ^ nb) & 7)) << 3)];
                    acc[i][g] = __builtin_amdgcn_mfma_f32_16x16x32_bf16(a, bfr, acc[i][g], 0, 0, 0);
                }
            }
        }
        #pragma unroll
        for (int i = 0; i < 2; ++i) {
            int trow = wr * 32 + i * 16 + lg * 4;
            #pragma unroll
            for (int g = 0; g < 4; ++g) {
                int co = (wc * 4 + g) * 16 + lr;
                float bv = bc[co];
                #pragma unroll
                for (int r = 0; r < 4; ++r) {
                    int t = t0 + trow + r;
                    att[((size_t)b * 8192 + t) * 256 + co] = f2bf(acc[i][g][r] + bv);
                }
            }
        }
    } else {
        u16* qkv = smem;             // 64*200
        const int QBASE = (path == 1) ? 128 : 320;
        const int OBASE = (path == 1) ? 128 : 192;
        const float* tab = (path == 1) ? tab1 : tab2;
        int j0 = (inner & 127) << 3;
        if (tid < 60) stab[tid] = tab[tid];
        for (int c = tid; c < 64 * 24; c += 256) {
            int ridx = c / 24, off = (c % 24) << 3;
            int wl = ridx >> 3, n = ridx & 7;
            int t = (path == 1) ? ((j0 + wl) * 8 + n) : (n * 1024 + j0 + wl);
            *(uint4*)&qkv[ridx * 200 + off] = *(const uint4*)&f[((size_t)b * 8192 + t) * 512 + QBASE + off];
        }
        __syncthreads();
        int wl = tid >> 5, h = (tid >> 3) & 3, n = tid & 7;
        const u16* qr = &qkv[(wl * 8 + n) * 200 + h * 16];
        float q[16];
        {
            short8 q0 = *(const short8*)qr, q1 = *(const short8*)(qr + 8);
            #pragma unroll
            for (int d = 0; d < 8; ++d) { q[d] = bf2f_s(q0[d]); q[d + 8] = bf2f_s(q1[d]); }
        }
        float s[8];
        #pragma unroll
        for (int m = 0; m < 8; ++m) {
            const u16* kr = &qkv[(wl * 8 + m) * 200 + 64 + h * 16];
            short8 k0 = *(const short8*)kr, k1 = *(const short8*)(kr + 8);
            float a = 0.f;
            #pragma unroll
            for (int d = 0; d < 8; ++d) a += q[d] * bf2f_s(k0[d]) + q[d + 8] * bf2f_s(k1[d]);
            s[m] = 0.5f * a + stab[(n - m + 7) * 4 + h];
        }
        float mx = s[0];
        #pragma unroll
        for (int m = 1; m < 8; ++m) mx = fmaxf(mx, s[m]);
        float sum = 0.f;
        #pragma unroll
        for (int m = 0; m < 8; ++m) { s[m] = __expf(s[m] - mx); sum += s[m]; }
        float rinv = 1.f / sum;
        float o[16] = {};
        #pragma unroll
        for (int m = 0; m < 8; ++m) {
            float p = s[m] * rinv;
            const u16* vr = &qkv[(wl * 8 + m) * 200 + 128 + h * 16];
            short8 v0 = *(const short8*)vr, v1 = *(const short8*)(vr + 8);
            #pragma unroll
            for (int d = 0; d < 8; ++d) { o[d] += p * bf2f_s(v0[d]); o[d + 8] += p * bf2f_s(v1[d]); }
        }
        int t = (path == 1) ? ((j0 + wl) * 8 + n) : (n * 1024 + j0 + wl);
        short8 o0, o1;
        #pragma unroll
        for (int d = 0; d < 8; ++d) { o0[d] = (short)f2bf(o[d]); o1[d] = (short)f2bf(o[d + 8]); }
        u16* op = &att[((size_t)b * 8192 + t) * 256 + OBASE + h * 16];
        *(short8*)op = o0; *(short8*)(op + 8) = o1;
    }
}

extern "C" void kernel_launch(void* const* d_in, const int* in_sizes, int n_in,
                              void* d_out, int out_size, void* d_ws, size_t ws_size,
                              hipStream_t stream) {
    const float* x    = (const float*)d_in[0];
    const float* g1   = (const float*)d_in[1];
    const float* b1   = (const float*)d_in[2];
    const float* Wm   = (const float*)d_in[3];
    const float* bm   = (const float*)d_in[4];
    const float* Wc   = (const float*)d_in[5];
    const float* bc   = (const float*)d_in[6];
    const float* tab1 = (const float*)d_in[7];
    const float* tab2 = (const float*)d_in[8];
    const float* Wp   = (const float*)d_in[9];
    const float* bp   = (const float*)d_in[10];
    const float* g2   = (const float*)d_in[11];
    const float* b2   = (const float*)d_in[12];
    const float* W1   = (const float*)d_in[13];
    const float* bf1  = (const float*)d_in[14];
    const float* W2   = (const float*)d_in[15];
    const float* bf2  = (const float*)d_in[16];
    float* out = (float*)d_out;

    char* ws = (char*)d_ws;
    // layout: f 134MB | att 67MB | outb 67MB | (unused) | xt 67MB | weights+stats ~3.5MB
    u16* f    = (u16*)(ws);
    u16* att  = (u16*)(ws + 134217728);
    u16* outb = (u16*)(ws + 201326592);
    u16* xt   = (u16*)(ws + 335544320);
    char* wb = ws + 402653184;
    u16* WmT    = (u16*)wb;                    // 262144 B
    u16* WpT    = (u16*)(wb + 262144);         // 131072 B
    u16* W1T    = (u16*)(wb + 393216);         // 524288 B
    u16* W2T    = (u16*)(wb + 917504);         // 524288 B
    u16* WtC    = (u16*)(wb + 1441792);        // 32768 B
    float* bmF  = (float*)(wb + 1474560);      // 2048 B
    float* b1F  = (float*)(wb + 1476608);      // 4096 B
    float* cs1  = (float*)(wb + 1480704);      // 2048 B  (colsum of g1*Wm)
    float* mbuf = (float*)(wb + 1482752);      // 524288 B
    float* rbuf = (float*)(wb + 2007040);      // 524288 B

    prep_weights<<<512, 256, 0, stream>>>(Wm, Wp, W1, W2, Wc, g1, b1, g2, b2, bm, bf1,
                                          WmT, WpT, W1T, W2T, WtC, bmF, b1F, cs1);
    ln1_kernel<<<Bb * (Tt / 64), 256, 0, stream>>>(x, xt, mbuf, rbuf);
    gemm_bt2<0, 512, 256><<<(M_TOT / 128) * 4, 256, 0, stream>>>(xt, WmT, bmF, f, nullptr,
                                                                 mbuf, rbuf, cs1);
    mixer_kernel<<<3 * Bb * 128, 256, 0, stream>>>(f, WtC, bc, tab1, tab2, att);
    gemm_bt2<1, 256, 256><<<(M_TOT / 128) * 2, 256, 0, stream>>>(att, WpT, bp, outb, xt,
                                                                 nullptr, nullptr, nullptr);
    ffn_fused7<<<M_TOT / 128, 1024, 0, stream>>>(outb, W1T, b1F, W2T, bf2, out);
}